// Round 6
// baseline (89.466 us; speedup 1.0000x reference)
//
#include <hip/hip_runtime.h>
#include <stdint.h>

// ---------------------------------------------------------------------------
// RDFBins: species-pair radial distribution histogram.
//   out[si, sj, b] = #(pairs with species(first)=si, species(second)=sj,
//                      bins[b] <= d < bins[b+1]) / n_molecules
// Inputs: pair_dist f32[NP], pair_first i32[NP], pair_second i32[NP],
//         one_hot bool[NA,4], n_molecules i32[1], bins f32[NE].
//
// R6: R3-R5 sat at an ADDITIVE pipe wall (~2.8 cy/pair/CU: mem 1.2 + LDS 0.9
// + VALU 0.5). Cut demand: (1) exact arithmetic binning (precheck proves
// floor((d-lo)*scale) == searchsorted for ALL floats; drops the eb ds_read);
// (2) per-block histogram -> coalesced stores -> tree-reduce kernel (kills
// the 512-deep global-atomic storm); (3) revert to simple grid-stride loop.
// ---------------------------------------------------------------------------

#define NSPEC 4
#define HIST_BLOCKS 512

// Element size of one_hot elements from count of nonzero 4-byte words in the
// first 4096 bytes (strict one-hot rows):
//   u8 -> 1024 nonzero words; f32/i32 -> 256; i64/f64 -> 128
__device__ inline int esize_from_nzw(unsigned int nzw) {
    if (nzw >= 640) return 1;
    if (nzw >= 192) return 4;
    return 8;
}

__device__ inline int get_species(const uint8_t* oh, int atom, int E) {
    if (E == 1) {
        uint32_t v = *(const uint32_t*)(oh + (size_t)atom * 4);
        if (v & 0x000000FFu) return 0;
        if (v & 0x0000FF00u) return 1;
        if (v & 0x00FF0000u) return 2;
        return 3;
    }
    const uint8_t* p = oh + (size_t)atom * 4 * E;
    for (int s = 0; s < NSPEC; ++s) {
        bool nzb = false;
        for (int b = 0; b < E; ++b) nzb |= (p[s * E + b] != 0);
        if (nzb) return s;
    }
    return 0;
}

// --- kernel 1: detect elem width, zero counts, pack species 2 bits/atom ----
__global__ void k_species(const uint8_t* __restrict__ oh, int n_atoms,
                          uint32_t* __restrict__ sp2,
                          unsigned int* __restrict__ counts, int n_counts) {
    __shared__ unsigned int s_nz;
    if (threadIdx.x == 0) s_nz = 0;
    __syncthreads();
    unsigned int local = 0;
    #pragma unroll
    for (int k = 0; k < 4; ++k) {  // 256 threads x 4 words = first 4096 B
        uint32_t v = ((const uint32_t*)oh)[threadIdx.x * 4 + k];
        local += (v != 0u);
    }
    for (int off = 32; off > 0; off >>= 1) local += __shfl_down(local, off);
    if ((threadIdx.x & 63) == 0) atomicAdd(&s_nz, local);
    __syncthreads();
    const int E = esize_from_nzw(s_nz);

    const int gid = blockIdx.x * blockDim.x + threadIdx.x;
    const int gsz = gridDim.x * blockDim.x;
    for (int j = gid; j < n_counts; j += gsz) counts[j] = 0u;

    const int nw = (n_atoms + 15) >> 4;
    for (int w = gid; w < nw; w += gsz) {
        uint32_t word = 0;
        int base = w << 4;
        int lim = n_atoms - base;
        lim = lim < 16 ? lim : 16;
        for (int k = 0; k < lim; ++k)
            word |= (uint32_t)get_species(oh, base + k, E) << (k * 2);
        sp2[w] = word;
    }
}

// --- kernel 2 (main): histogram, LDS species table -------------------------
// dyn LDS: float2 eb[n_bins] | uint32 tab[n_words] | int h[nh+8]
// part != nullptr: store block histogram to part[blockIdx*nh + j]
// part == nullptr: atomicAdd into counts
__launch_bounds__(1024, 8) __global__
void k_hist_lds(const float* __restrict__ dist, const int* __restrict__ pf,
                const int* __restrict__ ps, const uint32_t* __restrict__ sp2,
                const float* __restrict__ bins, int n_edges, int n_words,
                int npairs, unsigned int* __restrict__ counts,
                unsigned int* __restrict__ part) {
    extern __shared__ float2 smem2[];
    const int n_bins = n_edges - 1;
    const int nh = NSPEC * NSPEC * n_bins;
    float2* eb = smem2;
    uint32_t* tab = (uint32_t*)(eb + n_bins);
    int* h = (int*)(tab + n_words);
    __shared__ int s_exact;

    const int tid = threadIdx.x;
    if (tid == 0) s_exact = 1;
    __syncthreads();

    for (int j = tid; j < n_words; j += blockDim.x) tab[j] = sp2[j];
    for (int j = tid; j < nh + 8; j += blockDim.x) h[j] = 0;
    const float lo = bins[0];
    const float hi = bins[n_edges - 1];
    const float scale = (float)n_bins / (hi - lo);

    // Exactness precheck: g(d) = clamp((int)((d-lo)*scale), 0, n_bins-1) is a
    // monotone step fn; searchsorted(right)-1 jumps exactly at bins[j]. If
    // they agree at every edge and its predecessor float, they agree for ALL
    // d in [lo, hi). (Both monotone, same value on each breakpoint interval.)
    for (int j = tid; j < n_edges; j += blockDim.x) {
        float e = bins[j];
        eb[j < n_bins ? j : 0] = make_float2(bins[j < n_bins ? j : 0],
                                             bins[(j < n_bins ? j : 0) + 1]);
        bool ok = true;
        if (j < n_bins) {  // g(bins[j]) == j
            int gi = (int)((e - lo) * scale);
            gi = gi < n_bins - 1 ? gi : n_bins - 1;
            gi = gi > 0 ? gi : 0;
            ok &= (gi == j);
        }
        if (j >= 1) {  // g(pred(bins[j])) == j-1
            if (e <= 0.f) ok = false;
            else {
                float ep = __int_as_float(__float_as_int(e) - 1);
                int gi = (int)((ep - lo) * scale);
                gi = gi < n_bins - 1 ? gi : n_bins - 1;
                gi = gi > 0 ? gi : 0;
                ok &= (gi == j - 1);
            }
        }
        if (!ok) atomicAnd(&s_exact, 0);
    }
    __syncthreads();

    const int gid = blockIdx.x * blockDim.x + tid;
    const int gsz = gridDim.x * blockDim.x;
    const int nquads = npairs >> 2;
    const int dump = nh + (tid & 7);

    const float4* dist4 = (const float4*)dist;
    const int4* pf4 = (const int4*)pf;
    const int4* ps4 = (const int4*)ps;

    if (s_exact) {
        for (int q = gid; q < nquads; q += gsz) {
            float4 d4 = dist4[q];
            int4 f4 = pf4[q];
            int4 s4 = ps4[q];
            float d[4] = {d4.x, d4.y, d4.z, d4.w};
            int a0[4] = {f4.x, f4.y, f4.z, f4.w};
            int a1[4] = {s4.x, s4.y, s4.z, s4.w};
            uint32_t wi[4], wj[4];
            #pragma unroll
            for (int k = 0; k < 4; ++k) {
                wi[k] = tab[(unsigned)a0[k] >> 4];
                wj[k] = tab[(unsigned)a1[k] >> 4];
            }
            #pragma unroll
            for (int k = 0; k < 4; ++k) {
                int b = (int)((d[k] - lo) * scale);
                b = b < n_bins - 1 ? b : n_bins - 1;
                b = b > 0 ? b : 0;
                int vld = (d[k] >= lo) & (d[k] < hi);
                int si = (int)((wi[k] >> ((a0[k] & 15) << 1)) & 3u);
                int sj = (int)((wj[k] >> ((a1[k] & 15) << 1)) & 3u);
                int idx = (si * NSPEC + sj) * n_bins + b;
                atomicAdd(&h[vld ? idx : dump], 1);
            }
        }
    } else {
        // safe path: ±edge fix-up with while loops (non-uniform bins)
        for (int q = gid; q < nquads; q += gsz) {
            float4 d4 = dist4[q];
            int4 f4 = pf4[q];
            int4 s4 = ps4[q];
            float d[4] = {d4.x, d4.y, d4.z, d4.w};
            int a0[4] = {f4.x, f4.y, f4.z, f4.w};
            int a1[4] = {s4.x, s4.y, s4.z, s4.w};
            #pragma unroll
            for (int k = 0; k < 4; ++k) {
                if (d[k] >= lo && d[k] < hi) {
                    int b = (int)((d[k] - lo) * scale);
                    b = b < n_bins - 1 ? b : n_bins - 1;
                    b = b > 0 ? b : 0;
                    while (d[k] < eb[b].x) --b;
                    while (d[k] >= eb[b].y) ++b;
                    int s_i = (int)((tab[(unsigned)a0[k] >> 4] >>
                                     ((a0[k] & 15) << 1)) & 3u);
                    int s_j = (int)((tab[(unsigned)a1[k] >> 4] >>
                                     ((a1[k] & 15) << 1)) & 3u);
                    atomicAdd(&h[(s_i * NSPEC + s_j) * n_bins + b], 1);
                }
            }
        }
    }
    // tail (npairs % 4) — safe path
    int tail = npairs & 3;
    if (gid < tail) {
        int i = (nquads << 2) + gid;
        float d = dist[i];
        if (d >= lo && d < hi) {
            int b = (int)((d - lo) * scale);
            b = b < n_bins - 1 ? b : n_bins - 1;
            b = b > 0 ? b : 0;
            while (d < eb[b].x) --b;
            while (d >= eb[b].y) ++b;
            int a0 = pf[i], a1 = ps[i];
            int s_i = (int)((tab[(unsigned)a0 >> 4] >> ((a0 & 15) << 1)) & 3u);
            int s_j = (int)((tab[(unsigned)a1 >> 4] >> ((a1 & 15) << 1)) & 3u);
            atomicAdd(&h[(s_i * NSPEC + s_j) * n_bins + b], 1);
        }
    }

    __syncthreads();
    if (part) {
        unsigned int* dst = part + (size_t)blockIdx.x * nh;
        for (int j = tid; j < nh; j += blockDim.x) dst[j] = (unsigned int)h[j];
    } else {
        for (int j = tid; j < nh; j += blockDim.x) {
            int v = h[j];
            if (v) atomicAdd(&counts[j], (unsigned int)v);
        }
    }
}

// --- kernel 2 (fallback): global species table, for oversized inputs -------
__launch_bounds__(256, 8) __global__
void k_hist_glb(const float* __restrict__ dist, const int* __restrict__ pf,
                const int* __restrict__ ps, const uint32_t* __restrict__ sp2,
                const float* __restrict__ bins, int n_edges, int npairs,
                unsigned int* __restrict__ counts) {
    const int n_bins = n_edges - 1;
    const int nh = NSPEC * NSPEC * n_bins;
    extern __shared__ float smem[];
    float* sb = smem;
    int* h = (int*)(smem + n_edges);
    const int tid = threadIdx.x;
    for (int j = tid; j < n_edges; j += blockDim.x) sb[j] = bins[j];
    for (int j = tid; j < nh; j += blockDim.x) h[j] = 0;
    __syncthreads();
    const float lo = sb[0];
    const float hi = sb[n_edges - 1];
    const float scale = (float)n_bins / (hi - lo);
    const int gid = blockIdx.x * blockDim.x + tid;
    const int gsz = gridDim.x * blockDim.x;
    auto species_of = [&](int a) -> int {
        return (int)((sp2[a >> 4] >> ((a & 15) << 1)) & 3u);
    };
    auto bin_and_add = [&](float d, int si, int sj) {
        if (d >= lo && d < hi) {
            int b = (int)((d - lo) * scale);
            b = b < n_bins - 1 ? b : n_bins - 1;
            b = b > 0 ? b : 0;
            while (d < sb[b]) --b;
            while (d >= sb[b + 1]) ++b;
            atomicAdd(&h[(si * NSPEC + sj) * n_bins + b], 1);
        }
    };
    const int nquads = npairs >> 2;
    for (int q = gid; q < nquads; q += gsz) {
        float4 d4 = ((const float4*)dist)[q];
        int4 f4 = ((const int4*)pf)[q];
        int4 s4 = ((const int4*)ps)[q];
        bin_and_add(d4.x, species_of(f4.x), species_of(s4.x));
        bin_and_add(d4.y, species_of(f4.y), species_of(s4.y));
        bin_and_add(d4.z, species_of(f4.z), species_of(s4.z));
        bin_and_add(d4.w, species_of(f4.w), species_of(s4.w));
    }
    int tail = npairs & 3;
    if (gid < tail) {
        int i = (nquads << 2) + gid;
        bin_and_add(dist[i], species_of(pf[i]), species_of(ps[i]));
    }
    __syncthreads();
    for (int j = tid; j < nh; j += blockDim.x) {
        int v = h[j];
        if (v) atomicAdd(&counts[j], (unsigned int)v);
    }
}

// --- kernel 3a: tree-reduce partial histograms + normalize -----------------
// 8 lanes per bin; block = 256 threads = 32 bins.
__global__ void k_reduce(const unsigned int* __restrict__ part, int nblocks,
                         int nh, const int* __restrict__ nmol,
                         float* __restrict__ out) {
    const int tid = threadIdx.x;
    const int bin = blockIdx.x * 32 + (tid >> 3);
    const int sub = tid & 7;
    if (bin >= nh) return;
    unsigned int s = 0;
    for (int k = sub; k < nblocks; k += 8) s += part[(size_t)k * nh + bin];
    s += __shfl_down(s, 4);
    s += __shfl_down(s, 2);
    s += __shfl_down(s, 1);
    if (sub == 0) out[bin] = (float)s / (float)(*nmol);
}

// --- kernel 3b: normalize (atomic-counts path) ------------------------------
__global__ void k_final(const unsigned int* __restrict__ counts,
                        const int* __restrict__ nmol, float* __restrict__ out,
                        int n) {
    int i = blockIdx.x * blockDim.x + threadIdx.x;
    if (i < n) out[i] = (float)counts[i] / (float)(*nmol);
}

extern "C" void kernel_launch(void* const* d_in, const int* in_sizes, int n_in,
                              void* d_out, int out_size, void* d_ws,
                              size_t ws_size, hipStream_t stream) {
    const float* dist = (const float*)d_in[0];
    const int* pf = (const int*)d_in[1];
    const int* ps = (const int*)d_in[2];
    const uint8_t* oh = (const uint8_t*)d_in[3];
    const int* nmol = (const int*)d_in[4];
    const float* bins = (const float*)d_in[5];
    float* out = (float*)d_out;

    const int npairs = in_sizes[0];
    const int n_edges = in_sizes[5];
    const int n_bins = n_edges - 1;
    const int n_atoms = in_sizes[3] / NSPEC;
    const int nh = NSPEC * NSPEC * n_bins;  // 1600 for 101 edges

    uint8_t* ws = (uint8_t*)d_ws;
    unsigned int* counts = (unsigned int*)ws;         // nh u32
    uint32_t* sp2 = (uint32_t*)(ws + nh * 4 + 64);    // packed 2b/atom
    const int n_words = (n_atoms + 15) >> 4;
    size_t part_off = ((size_t)nh * 4 + 64 + (size_t)n_words * 4 + 255) &
                      ~(size_t)255;
    unsigned int* part = (unsigned int*)(ws + part_off);
    const size_t need_part = part_off + (size_t)HIST_BLOCKS * nh * 4;
    const bool use_tree = ws_size >= need_part;

    k_species<<<256, 256, 0, stream>>>(oh, n_atoms, sp2, counts, nh);

    const size_t shmem_lds = (size_t)n_bins * 8 + (size_t)n_words * 4 +
                             (size_t)(nh + 8) * 4;
    if (shmem_lds <= 64 * 1024) {
        k_hist_lds<<<HIST_BLOCKS, 1024, shmem_lds, stream>>>(
            dist, pf, ps, sp2, bins, n_edges, n_words, npairs, counts,
            use_tree ? part : nullptr);
    } else {
        const size_t shmem = (size_t)n_edges * 4 + (size_t)nh * 4;
        k_hist_glb<<<2048, 256, shmem, stream>>>(dist, pf, ps, sp2, bins,
                                                 n_edges, npairs, counts);
    }

    if (use_tree && shmem_lds <= 64 * 1024) {
        k_reduce<<<(nh + 31) / 32, 256, 0, stream>>>(part, HIST_BLOCKS, nh,
                                                     nmol, out);
    } else {
        k_final<<<(out_size + 255) / 256, 256, 0, stream>>>(counts, nmol, out,
                                                            out_size);
    }
}

// Round 7
// 80.557 us; speedup vs baseline: 1.1106x; 1.1106x over previous
//
#include <hip/hip_runtime.h>
#include <stdint.h>

// ---------------------------------------------------------------------------
// RDFBins: species-pair radial distribution histogram.
//   out[si, sj, b] = #(pairs with species(first)=si, species(second)=sj,
//                      bins[b] <= d < bins[b+1]) / n_molecules
// Inputs: pair_dist f32[NP], pair_first i32[NP], pair_second i32[NP],
//         one_hot bool[NA,4], n_molecules i32[1], bins f32[NE].
//
// R7: counters show nothing saturated (issue 4%, LDS 15%, feed 45%, VALU 21%)
// with ~6.4 waves/SIMD vs ~5.5 needed -> global-load-LATENCY-bound, marginal.
// Fix: depth-3 software pipeline (9 outstanding dwordx4/wave instead of 3),
// VGPR kept <=64 so 8 waves/SIMD survive. Tree-reduce reverted (cost net
// time in R6); atomic finish restored. Exact arithmetic binning kept.
// ---------------------------------------------------------------------------

#define NSPEC 4
#define HIST_BLOCKS 512

// Element size of one_hot elements from count of nonzero 4-byte words in the
// first 4096 bytes (strict one-hot rows):
//   u8 -> 1024 nonzero words; f32/i32 -> 256; i64/f64 -> 128
__device__ inline int esize_from_nzw(unsigned int nzw) {
    if (nzw >= 640) return 1;
    if (nzw >= 192) return 4;
    return 8;
}

__device__ inline int get_species(const uint8_t* oh, int atom, int E) {
    if (E == 1) {
        uint32_t v = *(const uint32_t*)(oh + (size_t)atom * 4);
        if (v & 0x000000FFu) return 0;
        if (v & 0x0000FF00u) return 1;
        if (v & 0x00FF0000u) return 2;
        return 3;
    }
    const uint8_t* p = oh + (size_t)atom * 4 * E;
    for (int s = 0; s < NSPEC; ++s) {
        bool nzb = false;
        for (int b = 0; b < E; ++b) nzb |= (p[s * E + b] != 0);
        if (nzb) return s;
    }
    return 0;
}

// --- kernel 1: detect elem width, zero counts, pack species 2 bits/atom ----
__global__ void k_species(const uint8_t* __restrict__ oh, int n_atoms,
                          uint32_t* __restrict__ sp2,
                          unsigned int* __restrict__ counts, int n_counts) {
    __shared__ unsigned int s_nz;
    if (threadIdx.x == 0) s_nz = 0;
    __syncthreads();
    unsigned int local = 0;
    #pragma unroll
    for (int k = 0; k < 4; ++k) {  // 256 threads x 4 words = first 4096 B
        uint32_t v = ((const uint32_t*)oh)[threadIdx.x * 4 + k];
        local += (v != 0u);
    }
    for (int off = 32; off > 0; off >>= 1) local += __shfl_down(local, off);
    if ((threadIdx.x & 63) == 0) atomicAdd(&s_nz, local);
    __syncthreads();
    const int E = esize_from_nzw(s_nz);

    const int gid = blockIdx.x * blockDim.x + threadIdx.x;
    const int gsz = gridDim.x * blockDim.x;
    for (int j = gid; j < n_counts; j += gsz) counts[j] = 0u;

    const int nw = (n_atoms + 15) >> 4;
    for (int w = gid; w < nw; w += gsz) {
        uint32_t word = 0;
        int base = w << 4;
        int lim = n_atoms - base;
        lim = lim < 16 ? lim : 16;
        for (int k = 0; k < lim; ++k)
            word |= (uint32_t)get_species(oh, base + k, E) << (k * 2);
        sp2[w] = word;
    }
}

// --- kernel 2 (main): depth-3 pipelined histogram, LDS species table -------
// dyn LDS: float2 eb[n_bins] | uint32 tab[n_words] | int h[nh+8]
__launch_bounds__(1024, 8) __global__
void k_hist_lds(const float* __restrict__ dist, const int* __restrict__ pf,
                const int* __restrict__ ps, const uint32_t* __restrict__ sp2,
                const float* __restrict__ bins, int n_edges, int n_words,
                int npairs, unsigned int* __restrict__ counts) {
    extern __shared__ float2 smem2[];
    const int n_bins = n_edges - 1;
    const int nh = NSPEC * NSPEC * n_bins;
    float2* eb = smem2;
    uint32_t* tab = (uint32_t*)(eb + n_bins);
    int* h = (int*)(tab + n_words);
    __shared__ int s_exact;

    const int tid = threadIdx.x;
    if (tid == 0) s_exact = 1;
    __syncthreads();

    for (int j = tid; j < n_words; j += blockDim.x) tab[j] = sp2[j];
    for (int j = tid; j < nh + 8; j += blockDim.x) h[j] = 0;
    for (int j = tid; j < n_bins; j += blockDim.x)
        eb[j] = make_float2(bins[j], bins[j + 1]);
    const float lo = bins[0];
    const float hi = bins[n_edges - 1];
    const float scale = (float)n_bins / (hi - lo);

    // Exactness precheck: g(d) = clamp((int)((d-lo)*scale), 0, n_bins-1) is a
    // monotone step fn; searchsorted(right)-1 jumps exactly at bins[j]. If
    // they agree at every edge and each edge's predecessor float, they agree
    // for ALL d in [lo, hi).
    for (int j = tid; j < n_edges; j += blockDim.x) {
        float e = bins[j];
        bool ok = true;
        if (j < n_bins) {  // g(bins[j]) == j
            int gi = (int)((e - lo) * scale);
            gi = gi < n_bins - 1 ? gi : n_bins - 1;
            gi = gi > 0 ? gi : 0;
            ok &= (gi == j);
        }
        if (j >= 1) {  // g(pred(bins[j])) == j-1
            if (e <= 0.f) ok = false;
            else {
                float ep = __int_as_float(__float_as_int(e) - 1);
                int gi = (int)((ep - lo) * scale);
                gi = gi < n_bins - 1 ? gi : n_bins - 1;
                gi = gi > 0 ? gi : 0;
                ok &= (gi == j - 1);
            }
        }
        if (!ok) atomicAnd(&s_exact, 0);
    }
    __syncthreads();

    const int gid = blockIdx.x * blockDim.x + tid;
    const int gsz = gridDim.x * blockDim.x;
    const int nquads = npairs >> 2;
    const int dump = nh + (tid & 7);

    const float4* dist4 = (const float4*)dist;
    const int4* pf4 = (const int4*)pf;
    const int4* ps4 = (const int4*)ps;

    if (s_exact) {
        // depth-3 software pipeline over grid-stride iterations
        const int last = nquads - 1;
        int n_iter = 0;
        if (gid < nquads) n_iter = (nquads - 1 - gid) / gsz + 1;

        float4 dA, dB, dC;
        int4 fA, fB, fC, sA, sB, sC;
        int idx = gid;

        #define LD(D, F, S, I)                 \
            do {                               \
                int c_ = (I);                  \
                c_ = c_ < last ? c_ : last;    \
                D = dist4[c_];                 \
                F = pf4[c_];                   \
                S = ps4[c_];                   \
            } while (0)

        #define CONSUME(D, F, S)                                            \
            do {                                                            \
                float d_[4] = {D.x, D.y, D.z, D.w};                         \
                int a0_[4] = {F.x, F.y, F.z, F.w};                          \
                int a1_[4] = {S.x, S.y, S.z, S.w};                          \
                uint32_t wi_[4], wj_[4];                                    \
                _Pragma("unroll") for (int k = 0; k < 4; ++k) {             \
                    wi_[k] = tab[(unsigned)a0_[k] >> 4];                    \
                    wj_[k] = tab[(unsigned)a1_[k] >> 4];                    \
                }                                                           \
                _Pragma("unroll") for (int k = 0; k < 4; ++k) {             \
                    int b_ = (int)((d_[k] - lo) * scale);                   \
                    b_ = b_ < n_bins - 1 ? b_ : n_bins - 1;                 \
                    b_ = b_ > 0 ? b_ : 0;                                   \
                    int vld_ = (d_[k] >= lo) & (d_[k] < hi);                \
                    int si_ = (int)((wi_[k] >> ((a0_[k] & 15) << 1)) & 3u); \
                    int sj_ = (int)((wj_[k] >> ((a1_[k] & 15) << 1)) & 3u); \
                    int hx_ = (si_ * NSPEC + sj_) * n_bins + b_;            \
                    atomicAdd(&h[vld_ ? hx_ : dump], 1);                    \
                }                                                           \
            } while (0)

        if (n_iter > 0) {
            LD(dA, fA, sA, idx);
            LD(dB, fB, sB, idx + gsz);
            LD(dC, fC, sC, idx + 2 * gsz);
            int it = 0;
            for (; it + 3 <= n_iter; it += 3) {
                CONSUME(dA, fA, sA);
                LD(dA, fA, sA, idx + 3 * gsz);
                idx += gsz;
                CONSUME(dB, fB, sB);
                LD(dB, fB, sB, idx + 3 * gsz);
                idx += gsz;
                CONSUME(dC, fC, sC);
                LD(dC, fC, sC, idx + 3 * gsz);
                idx += gsz;
            }
            if (it < n_iter) {
                CONSUME(dA, fA, sA);
                ++it;
                if (it < n_iter) {
                    CONSUME(dB, fB, sB);
                    ++it;
                    if (it < n_iter) CONSUME(dC, fC, sC);
                }
            }
        }
        #undef LD
        #undef CONSUME
    } else {
        // safe path: ±edge fix-up with while loops (non-uniform bins)
        for (int q = gid; q < nquads; q += gsz) {
            float4 d4 = dist4[q];
            int4 f4 = pf4[q];
            int4 s4 = ps4[q];
            float d[4] = {d4.x, d4.y, d4.z, d4.w};
            int a0[4] = {f4.x, f4.y, f4.z, f4.w};
            int a1[4] = {s4.x, s4.y, s4.z, s4.w};
            #pragma unroll
            for (int k = 0; k < 4; ++k) {
                if (d[k] >= lo && d[k] < hi) {
                    int b = (int)((d[k] - lo) * scale);
                    b = b < n_bins - 1 ? b : n_bins - 1;
                    b = b > 0 ? b : 0;
                    while (d[k] < eb[b].x) --b;
                    while (d[k] >= eb[b].y) ++b;
                    int s_i = (int)((tab[(unsigned)a0[k] >> 4] >>
                                     ((a0[k] & 15) << 1)) & 3u);
                    int s_j = (int)((tab[(unsigned)a1[k] >> 4] >>
                                     ((a1[k] & 15) << 1)) & 3u);
                    atomicAdd(&h[(s_i * NSPEC + s_j) * n_bins + b], 1);
                }
            }
        }
    }
    // tail (npairs % 4) — safe path
    int tail = npairs & 3;
    if (gid < tail) {
        int i = (nquads << 2) + gid;
        float d = dist[i];
        if (d >= lo && d < hi) {
            int b = (int)((d - lo) * scale);
            b = b < n_bins - 1 ? b : n_bins - 1;
            b = b > 0 ? b : 0;
            while (d < eb[b].x) --b;
            while (d >= eb[b].y) ++b;
            int a0 = pf[i], a1 = ps[i];
            int s_i = (int)((tab[(unsigned)a0 >> 4] >> ((a0 & 15) << 1)) & 3u);
            int s_j = (int)((tab[(unsigned)a1 >> 4] >> ((a1 & 15) << 1)) & 3u);
            atomicAdd(&h[(s_i * NSPEC + s_j) * n_bins + b], 1);
        }
    }

    __syncthreads();
    for (int j = tid; j < nh; j += blockDim.x) {
        int v = h[j];
        if (v) atomicAdd(&counts[j], (unsigned int)v);
    }
}

// --- kernel 2 (fallback): global species table, for oversized inputs -------
__launch_bounds__(256, 8) __global__
void k_hist_glb(const float* __restrict__ dist, const int* __restrict__ pf,
                const int* __restrict__ ps, const uint32_t* __restrict__ sp2,
                const float* __restrict__ bins, int n_edges, int npairs,
                unsigned int* __restrict__ counts) {
    const int n_bins = n_edges - 1;
    const int nh = NSPEC * NSPEC * n_bins;
    extern __shared__ float smem[];
    float* sb = smem;
    int* h = (int*)(smem + n_edges);
    const int tid = threadIdx.x;
    for (int j = tid; j < n_edges; j += blockDim.x) sb[j] = bins[j];
    for (int j = tid; j < nh; j += blockDim.x) h[j] = 0;
    __syncthreads();
    const float lo = sb[0];
    const float hi = sb[n_edges - 1];
    const float scale = (float)n_bins / (hi - lo);
    const int gid = blockIdx.x * blockDim.x + tid;
    const int gsz = gridDim.x * blockDim.x;
    auto species_of = [&](int a) -> int {
        return (int)((sp2[a >> 4] >> ((a & 15) << 1)) & 3u);
    };
    auto bin_and_add = [&](float d, int si, int sj) {
        if (d >= lo && d < hi) {
            int b = (int)((d - lo) * scale);
            b = b < n_bins - 1 ? b : n_bins - 1;
            b = b > 0 ? b : 0;
            while (d < sb[b]) --b;
            while (d >= sb[b + 1]) ++b;
            atomicAdd(&h[(si * NSPEC + sj) * n_bins + b], 1);
        }
    };
    const int nquads = npairs >> 2;
    for (int q = gid; q < nquads; q += gsz) {
        float4 d4 = ((const float4*)dist)[q];
        int4 f4 = ((const int4*)pf)[q];
        int4 s4 = ((const int4*)ps)[q];
        bin_and_add(d4.x, species_of(f4.x), species_of(s4.x));
        bin_and_add(d4.y, species_of(f4.y), species_of(s4.y));
        bin_and_add(d4.z, species_of(f4.z), species_of(s4.z));
        bin_and_add(d4.w, species_of(f4.w), species_of(s4.w));
    }
    int tail = npairs & 3;
    if (gid < tail) {
        int i = (nquads << 2) + gid;
        bin_and_add(dist[i], species_of(pf[i]), species_of(ps[i]));
    }
    __syncthreads();
    for (int j = tid; j < nh; j += blockDim.x) {
        int v = h[j];
        if (v) atomicAdd(&counts[j], (unsigned int)v);
    }
}

// --- kernel 3: normalize ----------------------------------------------------
__global__ void k_final(const unsigned int* __restrict__ counts,
                        const int* __restrict__ nmol, float* __restrict__ out,
                        int n) {
    int i = blockIdx.x * blockDim.x + threadIdx.x;
    if (i < n) out[i] = (float)counts[i] / (float)(*nmol);
}

extern "C" void kernel_launch(void* const* d_in, const int* in_sizes, int n_in,
                              void* d_out, int out_size, void* d_ws,
                              size_t ws_size, hipStream_t stream) {
    const float* dist = (const float*)d_in[0];
    const int* pf = (const int*)d_in[1];
    const int* ps = (const int*)d_in[2];
    const uint8_t* oh = (const uint8_t*)d_in[3];
    const int* nmol = (const int*)d_in[4];
    const float* bins = (const float*)d_in[5];
    float* out = (float*)d_out;

    const int npairs = in_sizes[0];
    const int n_edges = in_sizes[5];
    const int n_bins = n_edges - 1;
    const int n_atoms = in_sizes[3] / NSPEC;
    const int nh = NSPEC * NSPEC * n_bins;  // 1600 for 101 edges

    uint8_t* ws = (uint8_t*)d_ws;
    unsigned int* counts = (unsigned int*)ws;         // nh u32
    uint32_t* sp2 = (uint32_t*)(ws + nh * 4 + 64);    // packed 2b/atom
    const int n_words = (n_atoms + 15) >> 4;

    k_species<<<256, 256, 0, stream>>>(oh, n_atoms, sp2, counts, nh);

    const size_t shmem_lds = (size_t)n_bins * 8 + (size_t)n_words * 4 +
                             (size_t)(nh + 8) * 4;
    if (shmem_lds <= 64 * 1024) {
        k_hist_lds<<<HIST_BLOCKS, 1024, shmem_lds, stream>>>(
            dist, pf, ps, sp2, bins, n_edges, n_words, npairs, counts);
    } else {
        const size_t shmem = (size_t)n_edges * 4 + (size_t)nh * 4;
        k_hist_glb<<<2048, 256, shmem, stream>>>(dist, pf, ps, sp2, bins,
                                                 n_edges, npairs, counts);
    }

    k_final<<<(out_size + 255) / 256, 256, 0, stream>>>(counts, nmol, out,
                                                        out_size);
}